// Round 6
// baseline (58.581 us; speedup 1.0000x reference)
//
#include <hip/hip_runtime.h>
#include <hip/hip_bf16.h>
#include <math.h>

// ---------------------------------------------------------------------------
// KAN 2-layer forward, R6: barrier-free register-direct MFMA GEMM.
//   kconv_a: x(128,3072) -> Ag bf16[128][K=24576] (k=i*8+g), Asil bf16[128][3072]
//   kgemm  : C = A*W^T, W[o][k]=coef1[o][i][g]*ssp1[o][i] loaded fp32 register-
//            direct (one 32B run per lane per k-step), converted in-reg, MFMA.
//            + one extra k-step per chunk for sb*silu.  NO LDS, NO barriers.
//            split-K: 96 chunks of 32 i; f32 partial[kc][b][o].
//   kreduce: sum partials -> h, selu, layer2 -> out.
// ---------------------------------------------------------------------------

#define B_DIM   128
#define IN1     3072
#define OUT1    256
#define NB      8
#define OUT2    10

#define KTOT    (IN1 * 8)        // 24576
#define CI      32               // inputs per k-chunk
#define SPLITK  (IN1 / CI)       // 96
#define CPG     (SPLITK / 4)     // 24

typedef short  bf16x8 __attribute__((ext_vector_type(8)));
typedef float  f32x4  __attribute__((ext_vector_type(4)));
typedef unsigned short ushort_t;
typedef unsigned int u32;

__device__ __forceinline__ ushort_t f2bf(float f) {
    union { __hip_bfloat16 h; ushort_t u; } v;
    v.h = __float2bfloat16(f);
    return v.u;
}

__device__ __forceinline__ bf16x8 pack8(float a0, float a1, float a2, float a3,
                                        float a4, float a5, float a6, float a7) {
    union { ushort_t u[8]; bf16x8 v; } r;
    r.u[0] = f2bf(a0); r.u[1] = f2bf(a1); r.u[2] = f2bf(a2); r.u[3] = f2bf(a3);
    r.u[4] = f2bf(a4); r.u[5] = f2bf(a5); r.u[6] = f2bf(a6); r.u[7] = f2bf(a7);
    return r.v;
}

// cardinal cubic B-spline basis (8 funcs) + silu, closed form (== Cox-de Boor
// recursion of the reference on the uniform extended grid [-2.2,2.2], h=0.4).
__device__ __forceinline__ void basis_silu(float x, float w[8], float& sil) {
    sil = x / (1.0f + __expf(-x));
    float u  = (x + 2.2f) * 2.5f;
    float uf = floorf(u);
    int   j  = (int)uf;
    float t  = u - uf;
    float omt = 1.0f - t;
    float t2 = t * t, t3 = t2 * t;
    float w0 = omt * omt * omt * (1.0f / 6.0f);
    float w1 = (3.0f * t3 - 6.0f * t2 + 4.0f) * (1.0f / 6.0f);
    float w2 = (-3.0f * t3 + 3.0f * t2 + 3.0f * t + 1.0f) * (1.0f / 6.0f);
    float w3 = t3 * (1.0f / 6.0f);
    bool valid = (u >= 0.0f) && (u < 11.0f);
#pragma unroll
    for (int g = 0; g < 8; ++g) {
        int m = g - j + 3;
        float v = (m == 0) ? w0 : (m == 1) ? w1 : (m == 2) ? w2 : (m == 3) ? w3 : 0.0f;
        w[g] = valid ? v : 0.0f;
    }
}

__device__ __forceinline__ float selu_f(float x) {
    const float scale = 1.0507009873554805f;
    const float alpha = 1.6732632423543772f;
    return (x > 0.0f) ? scale * x : scale * alpha * (__expf(x) - 1.0f);
}

// ---------------------------------------------------------------------------
// kconv_a: thread -> (b, 8 inputs).  Ag[b][i*8+g] = basis_g(x[b,i]) bf16,
//          Asil[b][i] = silu(x[b,i]) bf16.
// ---------------------------------------------------------------------------
__global__ __launch_bounds__(256) void kconv_a(const float* __restrict__ x,
                                               char* __restrict__ Ag,
                                               char* __restrict__ Asil) {
    const int gid = blockIdx.x * 256 + threadIdx.x;     // 0..49151
    const int b  = gid / 384;
    const int ig = gid - b * 384;
    const int i0 = ig * 8;

    const float* xp = x + (size_t)b * IN1 + i0;
    float4 x0 = *reinterpret_cast<const float4*>(xp);
    float4 x1 = *reinterpret_cast<const float4*>(xp + 4);
    float xa[8] = {x0.x, x0.y, x0.z, x0.w, x1.x, x1.y, x1.z, x1.w};

    char* ap = Ag + ((size_t)b * KTOT + (size_t)i0 * 8) * 2;
    union { ushort_t u[8]; uint4 q; } sil;
#pragma unroll
    for (int p = 0; p < 8; ++p) {
        float bs[8], sl;
        basis_silu(xa[p], bs, sl);
        sil.u[p] = f2bf(sl);
        union { ushort_t u[8]; uint4 q; } t;
#pragma unroll
        for (int g = 0; g < 8; ++g) t.u[g] = f2bf(bs[g]);
        *reinterpret_cast<uint4*>(ap + p * 16) = t.q;
    }
    *reinterpret_cast<uint4*>(Asil + ((size_t)b * IN1 + i0) * 2) = sil.q;
}

// ---------------------------------------------------------------------------
// kgemm: grid (8 o-tiles of 32, 96 k-chunks of 32 i), 512 thr, no LDS.
//   wave w: mg=w>>1 (two 16-row m-tiles at mg*32), nq=w&1 (16 o-cols).
//   lane l: q=l>>4, r16=l&15;  o = o0 + nq*16 + r16.
//   k-step ks (0..7): i = i0 + ks*4 + q; B-frag = coef1[o][i][0..8)*ssp1[o][i].
//   step 8: B-frag = sb1[o][i0+q*8..+8), A-frag = Asil.
// ---------------------------------------------------------------------------
__global__ __launch_bounds__(512) void kgemm(const char* __restrict__ Ag,
                                             const char* __restrict__ Asil,
                                             const float* __restrict__ coef1,
                                             const float* __restrict__ sb1,
                                             const float* __restrict__ ssp1,
                                             float* __restrict__ partial) {
    const int tid = threadIdx.x;
    const int w   = tid >> 6, l = tid & 63;
    const int mg  = w >> 1, nq = w & 1;
    const int q   = l >> 4, r16 = l & 15;
    const int o0  = blockIdx.x * 32;
    const int kc  = blockIdx.y;
    const int i0  = kc * CI;
    const int o   = o0 + nq * 16 + r16;

    const float* cofp = coef1 + ((size_t)o * IN1 + i0 + q) * 8;
    const float* sspp = ssp1 + (size_t)o * IN1 + i0 + q;
    const char*  a0p  = Ag + ((size_t)(mg * 32 + r16) * KTOT + (size_t)(i0 + q) * 8) * 2;
    const char*  a1p  = a0p + (size_t)16 * KTOT * 2;

    f32x4 acc0 = {0.f, 0.f, 0.f, 0.f};
    f32x4 acc1 = {0.f, 0.f, 0.f, 0.f};

#pragma unroll
    for (int ks = 0; ks < 8; ++ks) {
        float4 c0 = *reinterpret_cast<const float4*>(cofp + ks * 32);
        float4 c1 = *reinterpret_cast<const float4*>(cofp + ks * 32 + 4);
        float  sv = sspp[ks * 4];
        bf16x8 bf = pack8(c0.x * sv, c0.y * sv, c0.z * sv, c0.w * sv,
                          c1.x * sv, c1.y * sv, c1.z * sv, c1.w * sv);
        bf16x8 a0 = *reinterpret_cast<const bf16x8*>(a0p + ks * 64);
        bf16x8 a1 = *reinterpret_cast<const bf16x8*>(a1p + ks * 64);
        acc0 = __builtin_amdgcn_mfma_f32_16x16x32_bf16(a0, bf, acc0, 0, 0, 0);
        acc1 = __builtin_amdgcn_mfma_f32_16x16x32_bf16(a1, bf, acc1, 0, 0, 0);
    }
    // silu/sb band: one more k-step spanning the chunk's 32 inputs
    {
        const float* sbp = sb1 + (size_t)o * IN1 + i0 + q * 8;
        float4 s0 = *reinterpret_cast<const float4*>(sbp);
        float4 s1 = *reinterpret_cast<const float4*>(sbp + 4);
        bf16x8 bf = pack8(s0.x, s0.y, s0.z, s0.w, s1.x, s1.y, s1.z, s1.w);
        const char* sa0 = Asil + ((size_t)(mg * 32 + r16) * IN1 + i0 + q * 8) * 2;
        const char* sa1 = sa0 + (size_t)16 * IN1 * 2;
        bf16x8 a0 = *reinterpret_cast<const bf16x8*>(sa0);
        bf16x8 a1 = *reinterpret_cast<const bf16x8*>(sa1);
        acc0 = __builtin_amdgcn_mfma_f32_16x16x32_bf16(a0, bf, acc0, 0, 0, 0);
        acc1 = __builtin_amdgcn_mfma_f32_16x16x32_bf16(a1, bf, acc1, 0, 0, 0);
    }

    // epilogue: f32 partial [kc][b][o]
    float* pp = partial + (size_t)kc * (B_DIM * OUT1);
#pragma unroll
    for (int r = 0; r < 4; ++r) {
        pp[(size_t)((mg * 2 + 0) * 16 + q * 4 + r) * OUT1 + o] = acc0[r];
        pp[(size_t)((mg * 2 + 1) * 16 + q * 4 + r) * OUT1 + o] = acc1[r];
    }
}

// ---------------------------------------------------------------------------
// kreduce: sum 96 partials (4-way split over 1024 thr) -> h, selu, layer2.
// ---------------------------------------------------------------------------
__global__ __launch_bounds__(1024) void kreduce(const float* __restrict__ partial,
                                                const float* __restrict__ coef2,
                                                const float* __restrict__ sb2,
                                                const float* __restrict__ ssp2,
                                                float* __restrict__ out) {
    const int b = blockIdx.x;
    const int t = threadIdx.x;
    const int o = t & 255;
    const int g = t >> 8;                    // 0..3
    const float* pp = partial + ((size_t)g * CPG * B_DIM + b) * OUT1 + o;
    float sum = 0.0f;
#pragma unroll
    for (int c = 0; c < CPG; ++c)
        sum += pp[(size_t)c * (B_DIM * OUT1)];

    __shared__ float hred[4][OUT1];
    hred[g][o] = sum;
    __syncthreads();
    const float hv = hred[0][o] + hred[1][o] + hred[2][o] + hred[3][o];

    const float sh = selu_f(hv);
    float w8[8], sil;
    basis_silu(sh, w8, sil);

    float accs[OUT2];
#pragma unroll
    for (int oo = 0; oo < OUT2; ++oo) {
        const float* cp = coef2 + ((size_t)oo * OUT1 + o) * NB;
        float4 c0 = *reinterpret_cast<const float4*>(cp);
        float4 c1 = *reinterpret_cast<const float4*>(cp + 4);
        float dot = w8[0] * c0.x + w8[1] * c0.y + w8[2] * c0.z + w8[3] * c0.w +
                    w8[4] * c1.x + w8[5] * c1.y + w8[6] * c1.z + w8[7] * c1.w;
        accs[oo] = sb2[oo * OUT1 + o] * sil + ssp2[oo * OUT1 + o] * dot;
    }

    __shared__ float red[16][OUT2];
    const int lane = t & 63, wv = t >> 6;
#pragma unroll
    for (int oo = 0; oo < OUT2; ++oo) {
        float v = accs[oo];
#pragma unroll
        for (int off = 32; off >= 1; off >>= 1) v += __shfl_xor(v, off, 64);
        if (lane == 0) red[wv][oo] = v;
    }
    __syncthreads();
    if (t < OUT2)
        out[b * OUT2 + t] = red[0][t] + red[1][t] + red[2][t] + red[3][t];
}

// ---------------------------------------------------------------------------
extern "C" void kernel_launch(void* const* d_in, const int* in_sizes, int n_in,
                              void* d_out, int out_size, void* d_ws, size_t ws_size,
                              hipStream_t stream) {
    const float* x     = (const float*)d_in[0];
    const float* coef1 = (const float*)d_in[1];
    const float* sb1   = (const float*)d_in[2];
    const float* ssp1  = (const float*)d_in[3];
    const float* coef2 = (const float*)d_in[4];
    const float* sb2   = (const float*)d_in[5];
    const float* ssp2  = (const float*)d_in[6];
    float* out = (float*)d_out;

    char*  Ag      = (char*)d_ws;                                   // 6,291,456 B
    char*  Asil    = Ag + (size_t)B_DIM * KTOT * 2;                 //   786,432 B
    float* partial = (float*)(Asil + (size_t)B_DIM * IN1 * 2);      // 12,582,912 B

    kconv_a<<<192, 256, 0, stream>>>(x, Ag, Asil);
    kgemm<<<dim3(OUT1 / 32, SPLITK), 512, 0, stream>>>(Ag, Asil, coef1, sb1, ssp1, partial);
    kreduce<<<B_DIM, 1024, 0, stream>>>(partial, coef2, sb2, ssp2, out);
}

// Round 7
// 53.851 us; speedup vs baseline: 1.0878x; 1.0878x over previous
//
#include <hip/hip_runtime.h>
#include <hip/hip_bf16.h>
#include <math.h>

// ---------------------------------------------------------------------------
// KAN 2-layer forward, R7 = R5 pipeline + two bandwidth probes (A/B ablation).
//   kprobe_in : stream-read 25.2 MB of coef1 (d_in)  -> per-thread sums to ws
//   kprobe_ws : stream-read 25.2 MB of scratch (d_ws) -> per-thread sums to ws
//   (identical code; only the source pointer differs.  Decides whether d_in
//    reads are capped at ~700 GB/s irrespective of access pattern.)
//   kconv_a / kconv_w / kgemm / kreduce: unchanged from R5 (passed, 44.8 us).
// ---------------------------------------------------------------------------

#define B_DIM   128
#define IN1     3072
#define OUT1    256
#define NB      8
#define OUT2    10

#define KTOT    27648            // 9 * 3072
#define ROWB    55296            // KTOT * 2 bytes per row
#define SPLITK  108              // k-chunks (each 256 k = 4 stages of 64 k)
#define BN      64

typedef short  bf16x8 __attribute__((ext_vector_type(8)));
typedef float  f32x4  __attribute__((ext_vector_type(4)));
typedef unsigned short ushort_t;
typedef unsigned int u32;

__device__ __forceinline__ ushort_t f2bf(float f) {
    union { __hip_bfloat16 h; ushort_t u; } v;
    v.h = __float2bfloat16(f);
    return v.u;
}
__device__ __forceinline__ float bf2f(ushort_t h) {
    union { float f; u32 u; } v; v.u = ((u32)h) << 16;
    return v.f;
}

__device__ __forceinline__ void gl_lds16(const void* g, void* l) {
    __builtin_amdgcn_global_load_lds(
        (const __attribute__((address_space(1))) u32*)g,
        (__attribute__((address_space(3))) u32*)l, 16, 0, 0);
}

// cardinal cubic B-spline basis (8 funcs) + silu, closed form (== Cox-de Boor
// recursion of the reference on the uniform extended grid [-2.2,2.2], h=0.4).
__device__ __forceinline__ void basis_silu(float x, float w[8], float& sil) {
    sil = x / (1.0f + __expf(-x));
    float u  = (x + 2.2f) * 2.5f;
    float uf = floorf(u);
    int   j  = (int)uf;
    float t  = u - uf;
    float omt = 1.0f - t;
    float t2 = t * t, t3 = t2 * t;
    float w0 = omt * omt * omt * (1.0f / 6.0f);
    float w1 = (3.0f * t3 - 6.0f * t2 + 4.0f) * (1.0f / 6.0f);
    float w2 = (-3.0f * t3 + 3.0f * t2 + 3.0f * t + 1.0f) * (1.0f / 6.0f);
    float w3 = t3 * (1.0f / 6.0f);
    bool valid = (u >= 0.0f) && (u < 11.0f);
#pragma unroll
    for (int g = 0; g < 8; ++g) {
        int m = g - j + 3;
        float v = (m == 0) ? w0 : (m == 1) ? w1 : (m == 2) ? w2 : (m == 3) ? w3 : 0.0f;
        w[g] = valid ? v : 0.0f;
    }
}

__device__ __forceinline__ float selu_f(float x) {
    const float scale = 1.0507009873554805f;
    const float alpha = 1.6732632423543772f;
    return (x > 0.0f) ? scale * x : scale * alpha * (__expf(x) - 1.0f);
}

// ---------------------------------------------------------------------------
// Probes: 1024 blocks x 256 thr; 6 independent float4 loads per thread
// (1,572,864 float4 = 25.166 MB).  16 waves/CU, ~98 KB in flight per CU.
// ---------------------------------------------------------------------------
__global__ __launch_bounds__(256) void kprobe_in(const float4* __restrict__ src,
                                                 float* __restrict__ dst) {
    const size_t tid = (size_t)blockIdx.x * 256 + threadIdx.x;
    float acc = 0.0f;
#pragma unroll
    for (int j = 0; j < 6; ++j) {
        float4 v = src[tid + (size_t)j * 262144];
        acc += v.x + v.y + v.z + v.w;
    }
    dst[tid] = acc;
}

__global__ __launch_bounds__(256) void kprobe_ws(const float4* __restrict__ src,
                                                 float* __restrict__ dst) {
    const size_t tid = (size_t)blockIdx.x * 256 + threadIdx.x;
    float acc = 0.0f;
#pragma unroll
    for (int j = 0; j < 6; ++j) {
        float4 v = src[tid + (size_t)j * 262144];
        acc += v.x + v.y + v.z + v.w;
    }
    dst[tid] = acc;
}

// ---------------------------------------------------------------------------
// kconv_a: thread -> (b, ig of 8 i).  Writes 9 bands x ushort8 (swizzled quad).
// ---------------------------------------------------------------------------
__global__ __launch_bounds__(128) void kconv_a(const float* __restrict__ x,
                                               char* __restrict__ Ag) {
    const int gid = blockIdx.x * 128 + threadIdx.x;        // 0..49151
    const int b  = gid / 384;
    const int ig = gid - b * 384;
    const int i0 = ig * 8;

    float4 x0 = *reinterpret_cast<const float4*>(x + (size_t)b * IN1 + i0);
    float4 x1 = *reinterpret_cast<const float4*>(x + (size_t)b * IN1 + i0 + 4);
    float xa[8] = {x0.x, x0.y, x0.z, x0.w, x1.x, x1.y, x1.z, x1.w};

    float bs[8][8], sil[8];
#pragma unroll
    for (int p = 0; p < 8; ++p) basis_silu(xa[p], bs[p], sil[p]);

    char* rowp = Ag + (size_t)b * ROWB;
    const int qsw = ((ig & 7) ^ (b & 7)) << 4;
#pragma unroll
    for (int s = 0; s < 9; ++s) {
        ushort_t v[8];
#pragma unroll
        for (int p = 0; p < 8; ++p)
            v[p] = f2bf((s < 8) ? bs[p][s] : sil[p]);
        *reinterpret_cast<uint4*>(rowp + (s * 48 + (ig >> 3)) * 128 + qsw) =
            *reinterpret_cast<const uint4*>(v);
    }
}

// ---------------------------------------------------------------------------
// kconv_w: thread -> (o, ig of 8 i).  W[k][o]: slot<8 = coef*ssp, slot8 = sb.
// ---------------------------------------------------------------------------
__global__ __launch_bounds__(128) void kconv_w(const float* __restrict__ coef1,
                                               const float* __restrict__ sb1,
                                               const float* __restrict__ ssp1,
                                               char* __restrict__ Wg) {
    const int gid = blockIdx.x * 128 + threadIdx.x;        // 0..98303
    const int o  = gid / 384;
    const int ig = gid - o * 384;
    const int i0 = ig * 8;

    float cf[8][8], sspv[8], sbv[8];
#pragma unroll
    for (int p = 0; p < 8; ++p) {
        const float* cp = coef1 + ((size_t)o * IN1 + i0 + p) * NB;
        float4 c0 = *reinterpret_cast<const float4*>(cp);
        float4 c1 = *reinterpret_cast<const float4*>(cp + 4);
        cf[p][0] = c0.x; cf[p][1] = c0.y; cf[p][2] = c0.z; cf[p][3] = c0.w;
        cf[p][4] = c1.x; cf[p][5] = c1.y; cf[p][6] = c1.z; cf[p][7] = c1.w;
    }
    {
        float4 s0 = *reinterpret_cast<const float4*>(ssp1 + (size_t)o * IN1 + i0);
        float4 s1 = *reinterpret_cast<const float4*>(ssp1 + (size_t)o * IN1 + i0 + 4);
        sspv[0]=s0.x; sspv[1]=s0.y; sspv[2]=s0.z; sspv[3]=s0.w;
        sspv[4]=s1.x; sspv[5]=s1.y; sspv[6]=s1.z; sspv[7]=s1.w;
        float4 b0 = *reinterpret_cast<const float4*>(sb1 + (size_t)o * IN1 + i0);
        float4 b1 = *reinterpret_cast<const float4*>(sb1 + (size_t)o * IN1 + i0 + 4);
        sbv[0]=b0.x; sbv[1]=b0.y; sbv[2]=b0.z; sbv[3]=b0.w;
        sbv[4]=b1.x; sbv[5]=b1.y; sbv[6]=b1.z; sbv[7]=b1.w;
    }

    char* rowp = Wg + (size_t)o * ROWB;
    const int qsw = ((ig & 7) ^ (o & 7)) << 4;
#pragma unroll
    for (int s = 0; s < 9; ++s) {
        ushort_t v[8];
#pragma unroll
        for (int p = 0; p < 8; ++p)
            v[p] = f2bf((s < 8) ? cf[p][s] * sspv[p] : sbv[p]);
        *reinterpret_cast<uint4*>(rowp + (s * 48 + (ig >> 3)) * 128 + qsw) =
            *reinterpret_cast<const uint4*>(v);
    }
}

// ---------------------------------------------------------------------------
// kgemm: C(128 x 64-per-nt) += A(128,256k) * W(256k,64).  512 thr, grid (4,108).
//   Stage = 64 k (one 128B chunk per row).  2-buffer LDS, counted vmcnt.
// ---------------------------------------------------------------------------
__global__ __launch_bounds__(512) void kgemm(const char* __restrict__ Ag,
                                             const char* __restrict__ Wg,
                                             ushort_t* __restrict__ partial) {
    __shared__ __align__(16) char lds[2][24576];   // per buf: A 16K | W 8K

    const int tid = threadIdx.x;
    const int w   = tid >> 6, l = tid & 63;
    const int nt  = blockIdx.x, kc = blockIdx.y;
    const int o0  = nt * BN;

    const int ar0 = tid >> 3;                 // A round 0: rows 0..63
    const int ar1 = 64 + (tid >> 3);          // A round 1: rows 64..127
    const int aq  = tid & 7;
    const char* Asrc0 = Ag + (size_t)ar0 * ROWB + ((aq ^ (ar0 & 7)) << 4);
    const char* Asrc1 = Ag + (size_t)ar1 * ROWB + ((aq ^ (ar1 & 7)) << 4);
    const int wr = tid >> 3;                  // W rows 0..63
    const char* Wsrc = Wg + (size_t)(o0 + wr) * ROWB + ((aq ^ (wr & 7)) << 4);

#define ISSUE(ss, buf)                                                        \
    {                                                                         \
        const int cb = (kc * 4 + (ss)) * 128;                                 \
        char* base = &lds[buf][0];                                            \
        gl_lds16(Asrc0 + cb, base + w * 1024);                                \
        gl_lds16(Asrc1 + cb, base + 8192 + w * 1024);                         \
        gl_lds16(Wsrc  + cb, base + 16384 + w * 1024);                        \
    }

    f32x4 acc[2][2];
#pragma unroll
    for (int a = 0; a < 2; ++a)
#pragma unroll
        for (int bq = 0; bq < 2; ++bq) acc[a][bq] = (f32x4){0.f, 0.f, 0.f, 0.f};

    const int mq = w >> 1, nq = w & 1;
    const int r16 = l & 15, k16 = l >> 4;

    ISSUE(0, 0)
    ISSUE(1, 1)

#pragma unroll
    for (int s = 0; s < 4; ++s) {
        if (s < 3) { asm volatile("s_waitcnt vmcnt(3)" ::: "memory"); }
        else       { asm volatile("s_waitcnt vmcnt(0)" ::: "memory"); }
        __builtin_amdgcn_s_barrier();
        asm volatile("" ::: "memory");

        const char* Ab = &lds[s & 1][0];
        const char* Wb = &lds[s & 1][16384];
#pragma unroll
        for (int ks = 0; ks < 2; ++ks) {
            const int qf = ks * 4 + k16;
            bf16x8 bf[2], af[2];
#pragma unroll
            for (int bq = 0; bq < 2; ++bq) {
                const int rn = nq * 32 + bq * 16 + r16;
                bf[bq] = *reinterpret_cast<const bf16x8*>(Wb + rn * 128 + ((qf ^ (rn & 7)) << 4));
            }
#pragma unroll
            for (int a = 0; a < 2; ++a) {
                const int rm = mq * 32 + a * 16 + r16;
                af[a] = *reinterpret_cast<const bf16x8*>(Ab + rm * 128 + ((qf ^ (rm & 7)) << 4));
            }
#pragma unroll
            for (int a = 0; a < 2; ++a)
#pragma unroll
                for (int bq = 0; bq < 2; ++bq)
                    acc[a][bq] = __builtin_amdgcn_mfma_f32_16x16x32_bf16(af[a], bf[bq], acc[a][bq], 0, 0, 0);
        }

        __builtin_amdgcn_s_barrier();
        asm volatile("" ::: "memory");
        if (s == 0) ISSUE(2, 0)
        if (s == 1) ISSUE(3, 1)
    }
#undef ISSUE

    // epilogue: bf16 partial [kc][b][o]
    ushort_t* pp = partial + (size_t)kc * (B_DIM * OUT1);
#pragma unroll
    for (int a = 0; a < 2; ++a) {
#pragma unroll
        for (int bq = 0; bq < 2; ++bq) {
            const int col = o0 + nq * 32 + bq * 16 + r16;
#pragma unroll
            for (int r = 0; r < 4; ++r) {
                const int row = mq * 32 + a * 16 + k16 * 4 + r;
                pp[(size_t)row * OUT1 + col] = f2bf(acc[a][bq][r]);
            }
        }
    }
}

// ---------------------------------------------------------------------------
// kreduce: sum 108 partials (4-way split) -> h, selu, layer2.
// ---------------------------------------------------------------------------
#define CPG (SPLITK / 4)   // 27

__global__ __launch_bounds__(1024) void kreduce(const ushort_t* __restrict__ partial,
                                                const float* __restrict__ coef2,
                                                const float* __restrict__ sb2,
                                                const float* __restrict__ ssp2,
                                                float* __restrict__ out) {
    const int b = blockIdx.x;
    const int t = threadIdx.x;
    const int o = t & 255;
    const int g = t >> 8;                    // 0..3
    const ushort_t* pp = partial + ((size_t)g * CPG * B_DIM + b) * OUT1 + o;
    float sum = 0.0f;
#pragma unroll
    for (int c = 0; c < CPG; ++c)
        sum += bf2f(pp[(size_t)c * (B_DIM * OUT1)]);

    __shared__ float hred[4][OUT1];
    hred[g][o] = sum;
    __syncthreads();
    const float hv = hred[0][o] + hred[1][o] + hred[2][o] + hred[3][o];

    const float sh = selu_f(hv);
    float w8[8], sil;
    basis_silu(sh, w8, sil);

    float accs[OUT2];
#pragma unroll
    for (int oo = 0; oo < OUT2; ++oo) {
        const float* cp = coef2 + ((size_t)oo * OUT1 + o) * NB;
        float4 c0 = *reinterpret_cast<const float4*>(cp);
        float4 c1 = *reinterpret_cast<const float4*>(cp + 4);
        float dot = w8[0] * c0.x + w8[1] * c0.y + w8[2] * c0.z + w8[3] * c0.w +
                    w8[4] * c1.x + w8[5] * c1.y + w8[6] * c1.z + w8[7] * c1.w;
        accs[oo] = sb2[oo * OUT1 + o] * sil + ssp2[oo * OUT1 + o] * dot;
    }

    __shared__ float red[16][OUT2];
    const int lane = t & 63, wv = t >> 6;
#pragma unroll
    for (int oo = 0; oo < OUT2; ++oo) {
        float v = accs[oo];
#pragma unroll
        for (int off = 32; off >= 1; off >>= 1) v += __shfl_xor(v, off, 64);
        if (lane == 0) red[wv][oo] = v;
    }
    __syncthreads();
    if (t < OUT2)
        out[b * OUT2 + t] = red[0][t] + red[1][t] + red[2][t] + red[3][t];
}

// ---------------------------------------------------------------------------
extern "C" void kernel_launch(void* const* d_in, const int* in_sizes, int n_in,
                              void* d_out, int out_size, void* d_ws, size_t ws_size,
                              hipStream_t stream) {
    const float* x     = (const float*)d_in[0];
    const float* coef1 = (const float*)d_in[1];
    const float* sb1   = (const float*)d_in[2];
    const float* ssp1  = (const float*)d_in[3];
    const float* coef2 = (const float*)d_in[4];
    const float* sb2   = (const float*)d_in[5];
    const float* ssp2  = (const float*)d_in[6];
    float* out = (float*)d_out;

    char*     Ag      = (char*)d_ws;                             // 7,077,888 B
    char*     Wg      = Ag + (size_t)B_DIM * ROWB;               // 14,155,776 B
    ushort_t* partial = (ushort_t*)(Wg + (size_t)OUT1 * ROWB);   // 7,077,888 B
    // probe areas (far past the live region; ws is poisoned 0xAA = tiny floats)
    float*    probeDstA = (float*)((char*)d_ws + (50u << 20));
    float*    probeDstB = (float*)((char*)d_ws + (52u << 20));
    const float4* probeSrcWs = (const float4*)((char*)d_ws + (64u << 20));

    kprobe_in<<<1024, 256, 0, stream>>>((const float4*)coef1, probeDstA);
    kprobe_ws<<<1024, 256, 0, stream>>>(probeSrcWs, probeDstB);
    kconv_a<<<384, 128, 0, stream>>>(x, Ag);
    kconv_w<<<768, 128, 0, stream>>>(coef1, sb1, ssp1, Wg);
    kgemm<<<dim3(OUT1 / BN, SPLITK), 512, 0, stream>>>(Ag, Wg, partial);
    kreduce<<<B_DIM, 1024, 0, stream>>>(partial, coef2, sb2, ssp2, out);
}